// Round 7
// baseline (506.334 us; speedup 1.0000x reference)
//
#include <hip/hip_runtime.h>
#include <math.h>

#define D 128

__device__ __forceinline__ float sigmoidf_(float x) { return 1.f / (1.f + __expf(-x)); }

// ---------------- fused prep: Wc | seg_off | b_sum,h1,c1  (partitioned by blockIdx) ----
__global__ void prep_kernel(const float* __restrict__ W_ih, const float* __restrict__ W_hh,
                            const float* __restrict__ b_ih, const float* __restrict__ b_hh,
                            const int* __restrict__ idx, int N, int G,
                            float* __restrict__ Wc, int* __restrict__ seg_off,
                            float* __restrict__ b_sum, float* __restrict__ h1,
                            float* __restrict__ c1) {
    int b = blockIdx.x, t = threadIdx.x;
    if (b < 256) {
        int i = b * 256 + t;
        int j = i >> 7, k = i & (D - 1);
        Wc[i] = W_ih[(size_t)j * (2 * D) + k] + W_hh[i];
    } else if (b < 273) {
        int g = (b - 256) * 256 + t;
        if (g <= G) {
            int lo = 0, hi = N;
            while (lo < hi) {
                int mid = (lo + hi) >> 1;
                if (idx[mid] < g) lo = mid + 1; else hi = mid;
            }
            seg_off[g] = lo;
        }
    } else {
        for (int i = t; i < 4 * D; i += 256) b_sum[i] = b_ih[i] + b_hh[i];
        if (t < D) {
            float bi = b_ih[t] + b_hh[t];
            float bg = b_ih[2 * D + t] + b_hh[2 * D + t];
            float bo = b_ih[3 * D + t] + b_hh[3 * D + t];
            float c = sigmoidf_(bi) * tanhf(bg);
            c1[t] = c;
            h1[t] = sigmoidf_(bo) * tanhf(c);
        }
    }
}

// ---------------- attention v4: LDS double-buffered tiles, decoupled streaming --------
// Tile = 32 rows (16 KB). Staging: pure global_load->ds_write (no arithmetic coupling).
// Compute: each wave takes 8 rows/tile from LDS (ds_read_b128), online softmax as before.
// One barrier per tile. Per-wave (m,s,acc) merged through LDS at the end.
__global__ __launch_bounds__(256) void attn_kernel(
    const float* __restrict__ x, const int* __restrict__ seg_off,
    const float* __restrict__ q, int q_stride,
    float* __restrict__ r_out, int r_stride, int G, int N) {
    int g = blockIdx.x;
    if (g >= G) return;
    int tid = threadIdx.x;
    int wave = tid >> 6, lane = tid & 63;
    int half = lane >> 5, col4 = lane & 31;

    __shared__ float xs[2][32 * D];   // 2 x 16 KB tiles
    __shared__ float sm[4], ss[4];
    __shared__ float sacc[4][D];

    int start = seg_off[g], end = seg_off[g + 1];
    int count = end - start;
    int T = (count + 31) >> 5;

    const float4* x4 = (const float4*)x;
    const float4* q4 = (const float4*)(q + (size_t)g * q_stride);
    float4 qv = q4[col4];

    float m = -INFINITY, s = 0.f;
    float4 acc = {0.f, 0.f, 0.f, 0.f};

    size_t gmax = (size_t)N * 32 - 1;   // clamp at float4 granularity (allocation-safe)

    if (T > 0) {   // stage tile 0
        size_t b4 = (size_t)start * 32;
        size_t i0 = b4 + tid, i1 = b4 + 256 + tid, i2 = b4 + 512 + tid, i3 = b4 + 768 + tid;
        float4 v0 = x4[i0 < gmax ? i0 : gmax];
        float4 v1 = x4[i1 < gmax ? i1 : gmax];
        float4 v2 = x4[i2 < gmax ? i2 : gmax];
        float4 v3 = x4[i3 < gmax ? i3 : gmax];
        *(float4*)&xs[0][(tid) * 4]       = v0;
        *(float4*)&xs[0][(256 + tid) * 4] = v1;
        *(float4*)&xs[0][(512 + tid) * 4] = v2;
        *(float4*)&xs[0][(768 + tid) * 4] = v3;
    }

    for (int t = 0; t < T; ++t) {
        int cur = t & 1;
        __syncthreads();   // staged tile t visible; prev iteration's reads done

        // issue next tile's loads (pure streaming, no dependence on compute chain)
        float4 st0, st1, st2, st3;
        bool more = (t + 1 < T);
        if (more) {
            size_t b4 = (size_t)(start + (t + 1) * 32) * 32;
            size_t i0 = b4 + tid, i1 = b4 + 256 + tid, i2 = b4 + 512 + tid, i3 = b4 + 768 + tid;
            st0 = x4[i0 < gmax ? i0 : gmax];
            st1 = x4[i1 < gmax ? i1 : gmax];
            st2 = x4[i2 < gmax ? i2 : gmax];
            st3 = x4[i3 < gmax ? i3 : gmax];
        }

        // compute this wave's 8 rows of tile t from LDS
        int tbase = t * 32 + wave * 8;        // row offset within segment
        if (tbase < count) {
            int vr = count - tbase;           // valid rows (>=1)
            const float* ls = &xs[cur][0];
            int rb = wave * 8 + half;
            float4 xa = *(const float4*)&ls[(rb + 0) * D + col4 * 4];
            float4 xb = *(const float4*)&ls[(rb + 2) * D + col4 * 4];
            float4 xc = *(const float4*)&ls[(rb + 4) * D + col4 * 4];
            float4 xd = *(const float4*)&ls[(rb + 6) * D + col4 * 4];

            float pa = xa.x * qv.x + xa.y * qv.y + xa.z * qv.z + xa.w * qv.w;
            float pb = xb.x * qv.x + xb.y * qv.y + xb.z * qv.z + xb.w * qv.w;
            float pc = xc.x * qv.x + xc.y * qv.y + xc.z * qv.z + xc.w * qv.w;
            float pd = xd.x * qv.x + xd.y * qv.y + xd.z * qv.z + xd.w * qv.w;
#pragma unroll
            for (int off = 1; off < 32; off <<= 1) {
                pa += __shfl_xor(pa, off);
                pb += __shfl_xor(pb, off);
                pc += __shfl_xor(pc, off);
                pd += __shfl_xor(pd, off);
            }
            float oa = __shfl_xor(pa, 32);
            float ob = __shfl_xor(pb, 32);
            float oc = __shfl_xor(pc, 32);
            float od = __shfl_xor(pd, 32);
            float pae = half ? oa : pa, pao = half ? pa : oa;
            float pbe = half ? ob : pb, pbo = half ? pb : ob;
            float pce = half ? oc : pc, pco = half ? pc : oc;
            float pde = half ? od : pd, pdo = half ? pd : od;
            pao = (1 < vr) ? pao : -INFINITY;
            pbe = (2 < vr) ? pbe : -INFINITY;
            pbo = (3 < vr) ? pbo : -INFINITY;
            pce = (4 < vr) ? pce : -INFINITY;
            pco = (5 < vr) ? pco : -INFINITY;
            pde = (6 < vr) ? pde : -INFINITY;
            pdo = (7 < vr) ? pdo : -INFINITY;

            float mn = fmaxf(fmaxf(fmaxf(pae, pao), fmaxf(pbe, pbo)),
                             fmaxf(fmaxf(pce, pco), fmaxf(pde, pdo)));
            mn = fmaxf(m, mn);
            float al = __expf(m - mn);
            float wae = __expf(pae - mn), wao = __expf(pao - mn);
            float wbe = __expf(pbe - mn), wbo = __expf(pbo - mn);
            float wce = __expf(pce - mn), wco = __expf(pco - mn);
            float wde = __expf(pde - mn), wdo = __expf(pdo - mn);
            float sg = (wae + wao) + (wbe + wbo) + ((wce + wco) + (wde + wdo));
            s = s * al + sg;
            float wsa = half ? wao : wae;
            float wsb = half ? wbo : wbe;
            float wsc = half ? wco : wce;
            float wsd = half ? wdo : wde;
            float tx = wsa * xa.x + wsb * xb.x + wsc * xc.x + wsd * xd.x;
            float ty = wsa * xa.y + wsb * xb.y + wsc * xc.y + wsd * xd.y;
            float tz = wsa * xa.z + wsb * xb.z + wsc * xc.z + wsd * xd.z;
            float tw = wsa * xa.w + wsb * xb.w + wsc * xc.w + wsd * xd.w;
            acc.x = acc.x * al + tx;
            acc.y = acc.y * al + ty;
            acc.z = acc.z * al + tz;
            acc.w = acc.w * al + tw;
            m = mn;
        }

        // write next tile into the other buffer (compiler inserts vmcnt wait here)
        if (more) {
            float* ld = &xs[1 - cur][0];
            *(float4*)&ld[(tid) * 4]       = st0;
            *(float4*)&ld[(256 + tid) * 4] = st1;
            *(float4*)&ld[(512 + tid) * 4] = st2;
            *(float4*)&ld[(768 + tid) * 4] = st3;
        }
    }

    acc.x += __shfl_xor(acc.x, 32);
    acc.y += __shfl_xor(acc.y, 32);
    acc.z += __shfl_xor(acc.z, 32);
    acc.w += __shfl_xor(acc.w, 32);

    if (lane == 0) { sm[wave] = m; ss[wave] = s; }
    if (half == 0) *(float4*)&sacc[wave][col4 * 4] = acc;
    __syncthreads();

    if (tid < D) {
        float m0 = sm[0], m1 = sm[1], m2 = sm[2], m3 = sm[3];
        float mstar = fmaxf(fmaxf(m0, m1), fmaxf(m2, m3));
        float r = 0.f;
        if (mstar > -INFINITY) {
            float e0 = __expf(m0 - mstar), e1 = __expf(m1 - mstar);
            float e2 = __expf(m2 - mstar), e3 = __expf(m3 - mstar);
            float stot = ss[0] * e0 + ss[1] * e1 + ss[2] * e2 + ss[3] * e3;
            float at = sacc[0][tid] * e0 + sacc[1][tid] * e1
                     + sacc[2][tid] * e2 + sacc[3][tid] * e3;
            r = at / fmaxf(stot, 1e-16f);
        }
        r_out[(size_t)g * r_stride + tid] = r;
    }
}

// ---------------- gates GEMM: 64x64 tile, 4x4 micro-tile, KC=32, 512 blocks ------
__global__ __launch_bounds__(256) void gates_gemm_kernel(
    const float* __restrict__ A1, int sA1,
    const float* __restrict__ W1,
    const float* __restrict__ A2,
    const float* __restrict__ W2, int sW2,
    const float* __restrict__ bias,
    float* __restrict__ gates) {
    __shared__ float As[32][72];
    __shared__ float Ws[32][72];
    int t = threadIdx.x;
    int tx = t & 15, ty = t >> 4;
    int g0 = blockIdx.x * 64, j0 = blockIdx.y * 64;
    int lr = t & 63;
    int lk = (t >> 6) * 8;

    float acc[4][4];
#pragma unroll
    for (int i = 0; i < 4; ++i)
#pragma unroll
        for (int j = 0; j < 4; ++j) acc[i][j] = 0.f;

    for (int phase = 0; phase < 2; ++phase) {
        const float* A = phase ? A2 : A1;
        int sA = phase ? D : sA1;
        const float* W = phase ? W2 : W1;
        int sW = phase ? sW2 : D;
        for (int kk = 0; kk < D; kk += 32) {
            float4 a0 = *(const float4*)&A[(size_t)(g0 + lr) * sA + kk + lk];
            float4 a1 = *(const float4*)&A[(size_t)(g0 + lr) * sA + kk + lk + 4];
            float4 w0 = *(const float4*)&W[(size_t)(j0 + lr) * sW + kk + lk];
            float4 w1 = *(const float4*)&W[(size_t)(j0 + lr) * sW + kk + lk + 4];
            __syncthreads();
            As[lk + 0][lr] = a0.x; As[lk + 1][lr] = a0.y; As[lk + 2][lr] = a0.z; As[lk + 3][lr] = a0.w;
            As[lk + 4][lr] = a1.x; As[lk + 5][lr] = a1.y; As[lk + 6][lr] = a1.z; As[lk + 7][lr] = a1.w;
            Ws[lk + 0][lr] = w0.x; Ws[lk + 1][lr] = w0.y; Ws[lk + 2][lr] = w0.z; Ws[lk + 3][lr] = w0.w;
            Ws[lk + 4][lr] = w1.x; Ws[lk + 5][lr] = w1.y; Ws[lk + 6][lr] = w1.z; Ws[lk + 7][lr] = w1.w;
            __syncthreads();
#pragma unroll
            for (int k = 0; k < 32; ++k) {
                float4 av = *(const float4*)&As[k][ty * 4];
                float4 bv = *(const float4*)&Ws[k][tx * 4];
                float aa[4] = {av.x, av.y, av.z, av.w};
                float bb[4] = {bv.x, bv.y, bv.z, bv.w};
#pragma unroll
                for (int i = 0; i < 4; ++i)
#pragma unroll
                    for (int j = 0; j < 4; ++j)
                        acc[i][j] = fmaf(aa[i], bb[j], acc[i][j]);
            }
        }
    }
#pragma unroll
    for (int i = 0; i < 4; ++i) {
        size_t row = (size_t)(g0 + ty * 4 + i);
        int jb = j0 + tx * 4;
        float4 o;
        o.x = acc[i][0] + bias[jb + 0];
        o.y = acc[i][1] + bias[jb + 1];
        o.z = acc[i][2] + bias[jb + 2];
        o.w = acc[i][3] + bias[jb + 3];
        *(float4*)&gates[row * 512 + jb] = o;
    }
}

// ---------------- LSTM cell elementwise ----------------
__global__ void cell_kernel(const float* __restrict__ gates,
                            const float* __restrict__ c_prev, int c_stride,
                            float* __restrict__ c_out,
                            float* __restrict__ h_out, int h_stride,
                            int total) {
    int t = blockIdx.x * blockDim.x + threadIdx.x;
    if (t >= total) return;
    int g = t >> 7, k = t & (D - 1);
    const float* grow = gates + (size_t)g * 512;
    float ig = grow[k];
    float fg = grow[D + k];
    float gg = grow[2 * D + k];
    float og = grow[3 * D + k];
    float cp = c_prev[(size_t)g * c_stride + k];
    float c = sigmoidf_(fg) * cp + sigmoidf_(ig) * tanhf(gg);
    float h = sigmoidf_(og) * tanhf(c);
    c_out[t] = c;
    h_out[(size_t)g * h_stride + k] = h;
}

extern "C" void kernel_launch(void* const* d_in, const int* in_sizes, int n_in,
                              void* d_out, int out_size, void* d_ws, size_t ws_size,
                              hipStream_t stream) {
    const float* x      = (const float*)d_in[0];
    const float* W_ih   = (const float*)d_in[1];
    const float* W_hh   = (const float*)d_in[2];
    const float* b_ih   = (const float*)d_in[3];
    const float* b_hh   = (const float*)d_in[4];
    const int*   index  = (const int*)d_in[5];
    int N = in_sizes[5];
    int G = out_size / (2 * D);
    float* out = (float*)d_out;

    float* ws = (float*)d_ws;
    float* Wc     = ws;                         // 512*D
    float* b_sum  = Wc + 4 * D * D;             // 512
    float* h1     = b_sum + 4 * D;              // D
    float* c1     = h1 + D;                     // D
    float* r1     = c1 + D;                     // G*D
    float* h2     = r1 + (size_t)G * D;         // G*D
    float* c2     = h2 + (size_t)G * D;         // G*D
    float* r2     = c2 + (size_t)G * D;         // G*D
    float* gatesb = r2 + (size_t)G * D;         // G*4D
    int* seg_off  = (int*)(gatesb + (size_t)G * 4 * D);
    float* c3     = r1;  // r1 dead after step-3 GEMM; c3 never read

    prep_kernel<<<274, 256, 0, stream>>>(W_ih, W_hh, b_ih, b_hh, index, N, G,
                                         Wc, seg_off, b_sum, h1, c1);

    // ---- step 1: attention with broadcast q = h1
    attn_kernel<<<G, 256, 0, stream>>>(x, seg_off, h1, 0, r1, D, G, N);

    // ---- step 2
    gates_gemm_kernel<<<dim3(G / 64, 8), 256, 0, stream>>>(
        h1, 0, Wc, r1, W_ih + D, 2 * D, b_sum, gatesb);
    cell_kernel<<<(G * D + 255) / 256, 256, 0, stream>>>(gatesb, c1, 0, c2, h2, D, G * D);
    attn_kernel<<<G, 256, 0, stream>>>(x, seg_off, h2, D, r2, D, G, N);

    // ---- step 3
    gates_gemm_kernel<<<dim3(G / 64, 8), 256, 0, stream>>>(
        h2, D, Wc, r2, W_ih + D, 2 * D, b_sum, gatesb);
    cell_kernel<<<(G * D + 255) / 256, 256, 0, stream>>>(gatesb, c2, D, c3, out, 2 * D, G * D);
    attn_kernel<<<G, 256, 0, stream>>>(x, seg_off, out, 2 * D, out + D, 2 * D, G, N);
}

// Round 8
// 492.303 us; speedup vs baseline: 1.0285x; 1.0285x over previous
//
#include <hip/hip_runtime.h>
#include <hip/hip_fp16.h>
#include <math.h>

#define D 128

__device__ __forceinline__ float sigmoidf_(float x) { return 1.f / (1.f + __expf(-x)); }

// ---------------- fused prep: Wc | seg_off | b_sum,h1,c1 ----------------
__global__ void prep_kernel(const float* __restrict__ W_ih, const float* __restrict__ W_hh,
                            const float* __restrict__ b_ih, const float* __restrict__ b_hh,
                            const int* __restrict__ idx, int N, int G,
                            float* __restrict__ Wc, int* __restrict__ seg_off,
                            float* __restrict__ b_sum, float* __restrict__ h1,
                            float* __restrict__ c1) {
    int b = blockIdx.x, t = threadIdx.x;
    if (b < 256) {
        int i = b * 256 + t;
        int j = i >> 7, k = i & (D - 1);
        Wc[i] = W_ih[(size_t)j * (2 * D) + k] + W_hh[i];
    } else if (b < 273) {
        int g = (b - 256) * 256 + t;
        if (g <= G) {
            int lo = 0, hi = N;
            while (lo < hi) {
                int mid = (lo + hi) >> 1;
                if (idx[mid] < g) lo = mid + 1; else hi = mid;
            }
            seg_off[g] = lo;
        }
    } else {
        for (int i = t; i < 4 * D; i += 256) b_sum[i] = b_ih[i] + b_hh[i];
        if (t < D) {
            float bi = b_ih[t] + b_hh[t];
            float bg = b_ih[2 * D + t] + b_hh[2 * D + t];
            float bo = b_ih[3 * D + t] + b_hh[3 * D + t];
            float c = sigmoidf_(bi) * tanhf(bg);
            c1[t] = c;
            h1[t] = sigmoidf_(bo) * tanhf(c);
        }
    }
}

// ---------------- x (fp32) -> xh (fp16), pure stream ----------------
__global__ __launch_bounds__(256) void x_to_h_kernel(const float* __restrict__ x,
                                                     __half* __restrict__ xh,
                                                     size_t total) {
    size_t i = ((size_t)blockIdx.x * 256 + threadIdx.x) * 8;
    if (i >= total) return;
    float4 a = *(const float4*)&x[i];
    float4 b = *(const float4*)&x[i + 4];
    __half2 h[4];
    h[0] = __floats2half2_rn(a.x, a.y);
    h[1] = __floats2half2_rn(a.z, a.w);
    h[2] = __floats2half2_rn(b.x, b.y);
    h[3] = __floats2half2_rn(b.z, b.w);
    *(float4*)&xh[i] = *(float4*)h;
}

// ---------------- attention v5: fp16 x, quarter-wave per row, 8 rows/iter ----------
// lane = qg*16 + c: group qg in [0,4) takes row base+qg (and base+4+qg), lane c covers
// cols 8c..8c+7 (one 16B load). Intra-group reduce (4 shfl) + cross-group gather (3 shfl)
// per 4 rows; single online-softmax update per 8 rows; scores/acc in fp32.
__global__ __launch_bounds__(256) void attn_kernel(
    const __half* __restrict__ xh, const int* __restrict__ seg_off,
    const float* __restrict__ q, int q_stride,
    float* __restrict__ r_out, int r_stride, int G) {
    int g = blockIdx.x;
    if (g >= G) return;
    int tid = threadIdx.x;
    int wave = tid >> 6, lane = tid & 63;
    int qg = lane >> 4;       // row group 0..3
    int c = lane & 15;        // 8-col chunk

    __shared__ float sm[4], ss[4];
    __shared__ float sacc[4][D];

    int start = seg_off[g], end = seg_off[g + 1];
    int count = end - start;
    int chunk = (count + 3) >> 2;
    int wsr = start + wave * chunk;
    int wer = min(wsr + chunk, end);

    const float4* x4 = (const float4*)xh;      // 16 float4 per row (128 halfs)
    const float* qrow = q + (size_t)g * q_stride;
    float4 q0 = *(const float4*)&qrow[8 * c];
    float4 q1 = *(const float4*)&qrow[8 * c + 4];

    float m = -INFINITY, s = 0.f;
    float acc[8] = {0.f, 0.f, 0.f, 0.f, 0.f, 0.f, 0.f, 0.f};

    if (wsr < wer) {
        int last = wer - 1;
        for (int base = wsr; base < wer; base += 8) {
            int r0 = min(base + qg, last);
            int r1 = min(base + 4 + qg, last);
            float4 v0 = x4[(size_t)r0 * 16 + c];
            float4 v1 = x4[(size_t)r1 * 16 + c];
            const __half2* h0 = (const __half2*)&v0;
            const __half2* h1 = (const __half2*)&v1;
            float2 a0 = __half22float2(h0[0]), a1 = __half22float2(h0[1]);
            float2 a2 = __half22float2(h0[2]), a3 = __half22float2(h0[3]);
            float2 b0 = __half22float2(h1[0]), b1 = __half22float2(h1[1]);
            float2 b2 = __half22float2(h1[2]), b3 = __half22float2(h1[3]);
            float xf0[8] = {a0.x, a0.y, a1.x, a1.y, a2.x, a2.y, a3.x, a3.y};
            float xf1[8] = {b0.x, b0.y, b1.x, b1.y, b2.x, b2.y, b3.x, b3.y};

            float p0 = xf0[0] * q0.x + xf0[1] * q0.y + xf0[2] * q0.z + xf0[3] * q0.w
                     + xf0[4] * q1.x + xf0[5] * q1.y + xf0[6] * q1.z + xf0[7] * q1.w;
            float p1 = xf1[0] * q0.x + xf1[1] * q0.y + xf1[2] * q0.z + xf1[3] * q0.w
                     + xf1[4] * q1.x + xf1[5] * q1.y + xf1[6] * q1.z + xf1[7] * q1.w;
#pragma unroll
            for (int off = 1; off < 16; off <<= 1) {
                p0 += __shfl_xor(p0, off);
                p1 += __shfl_xor(p1, off);
            }
            // gather the other 3 groups' scores
            float p0a = __shfl_xor(p0, 16), p0b = __shfl_xor(p0, 32), p0c = __shfl_xor(p0a, 32);
            float p1a = __shfl_xor(p1, 16), p1b = __shfl_xor(p1, 32), p1c = __shfl_xor(p1a, 32);
            // mask by row validity (row of pXa is base+(qg^1), etc.)
            float s00 = (base + qg       < wer) ? p0  : -INFINITY;
            float s01 = (base + (qg ^ 1) < wer) ? p0a : -INFINITY;
            float s02 = (base + (qg ^ 2) < wer) ? p0b : -INFINITY;
            float s03 = (base + (qg ^ 3) < wer) ? p0c : -INFINITY;
            float s10 = (base + 4 + qg       < wer) ? p1  : -INFINITY;
            float s11 = (base + 4 + (qg ^ 1) < wer) ? p1a : -INFINITY;
            float s12 = (base + 4 + (qg ^ 2) < wer) ? p1b : -INFINITY;
            float s13 = (base + 4 + (qg ^ 3) < wer) ? p1c : -INFINITY;

            float mn = fmaxf(fmaxf(fmaxf(s00, s01), fmaxf(s02, s03)),
                             fmaxf(fmaxf(s10, s11), fmaxf(s12, s13)));
            mn = fmaxf(m, mn);
            float al = __expf(m - mn);
            float w00 = __expf(s00 - mn), w01 = __expf(s01 - mn);
            float w02 = __expf(s02 - mn), w03 = __expf(s03 - mn);
            float w10 = __expf(s10 - mn), w11 = __expf(s11 - mn);
            float w12 = __expf(s12 - mn), w13 = __expf(s13 - mn);
            float sg = (w00 + w01) + (w02 + w03) + ((w10 + w11) + (w12 + w13));
            s = s * al + sg;
            // own-row weights (w00/w10 are already this lane's rows; invalid -> 0)
#pragma unroll
            for (int j = 0; j < 8; ++j)
                acc[j] = acc[j] * al + w00 * xf0[j] + w10 * xf1[j];
            m = mn;
        }
    }
    // merge across the 4 row-groups (same c, different qg)
#pragma unroll
    for (int j = 0; j < 8; ++j) {
        acc[j] += __shfl_xor(acc[j], 16);
        acc[j] += __shfl_xor(acc[j], 32);
    }
    if (lane == 0) { sm[wave] = m; ss[wave] = s; }
    if (qg == 0) {
#pragma unroll
        for (int j = 0; j < 8; ++j) sacc[wave][8 * c + j] = acc[j];
    }
    __syncthreads();

    if (tid < D) {
        float m0 = sm[0], m1 = sm[1], m2 = sm[2], m3 = sm[3];
        float mstar = fmaxf(fmaxf(m0, m1), fmaxf(m2, m3));
        float r = 0.f;
        if (mstar > -INFINITY) {
            float e0 = __expf(m0 - mstar), e1 = __expf(m1 - mstar);
            float e2 = __expf(m2 - mstar), e3 = __expf(m3 - mstar);
            float stot = ss[0] * e0 + ss[1] * e1 + ss[2] * e2 + ss[3] * e3;
            float at = sacc[0][tid] * e0 + sacc[1][tid] * e1
                     + sacc[2][tid] * e2 + sacc[3][tid] * e3;
            r = at / fmaxf(stot, 1e-16f);
        }
        r_out[(size_t)g * r_stride + tid] = r;
    }
}

// ---------------- gates GEMM: 64x64 tile, 4x4 micro-tile, KC=32 ----------------
__global__ __launch_bounds__(256) void gates_gemm_kernel(
    const float* __restrict__ A1, int sA1,
    const float* __restrict__ W1,
    const float* __restrict__ A2,
    const float* __restrict__ W2, int sW2,
    const float* __restrict__ bias,
    float* __restrict__ gates) {
    __shared__ float As[32][72];
    __shared__ float Ws[32][72];
    int t = threadIdx.x;
    int tx = t & 15, ty = t >> 4;
    int g0 = blockIdx.x * 64, j0 = blockIdx.y * 64;
    int lr = t & 63;
    int lk = (t >> 6) * 8;

    float acc[4][4];
#pragma unroll
    for (int i = 0; i < 4; ++i)
#pragma unroll
        for (int j = 0; j < 4; ++j) acc[i][j] = 0.f;

    for (int phase = 0; phase < 2; ++phase) {
        const float* A = phase ? A2 : A1;
        int sA = phase ? D : sA1;
        const float* W = phase ? W2 : W1;
        int sW = phase ? sW2 : D;
        for (int kk = 0; kk < D; kk += 32) {
            float4 a0 = *(const float4*)&A[(size_t)(g0 + lr) * sA + kk + lk];
            float4 a1 = *(const float4*)&A[(size_t)(g0 + lr) * sA + kk + lk + 4];
            float4 w0 = *(const float4*)&W[(size_t)(j0 + lr) * sW + kk + lk];
            float4 w1 = *(const float4*)&W[(size_t)(j0 + lr) * sW + kk + lk + 4];
            __syncthreads();
            As[lk + 0][lr] = a0.x; As[lk + 1][lr] = a0.y; As[lk + 2][lr] = a0.z; As[lk + 3][lr] = a0.w;
            As[lk + 4][lr] = a1.x; As[lk + 5][lr] = a1.y; As[lk + 6][lr] = a1.z; As[lk + 7][lr] = a1.w;
            Ws[lk + 0][lr] = w0.x; Ws[lk + 1][lr] = w0.y; Ws[lk + 2][lr] = w0.z; Ws[lk + 3][lr] = w0.w;
            Ws[lk + 4][lr] = w1.x; Ws[lk + 5][lr] = w1.y; Ws[lk + 6][lr] = w1.z; Ws[lk + 7][lr] = w1.w;
            __syncthreads();
#pragma unroll
            for (int k = 0; k < 32; ++k) {
                float4 av = *(const float4*)&As[k][ty * 4];
                float4 bv = *(const float4*)&Ws[k][tx * 4];
                float aa[4] = {av.x, av.y, av.z, av.w};
                float bb[4] = {bv.x, bv.y, bv.z, bv.w};
#pragma unroll
                for (int i = 0; i < 4; ++i)
#pragma unroll
                    for (int j = 0; j < 4; ++j)
                        acc[i][j] = fmaf(aa[i], bb[j], acc[i][j]);
            }
        }
    }
#pragma unroll
    for (int i = 0; i < 4; ++i) {
        size_t row = (size_t)(g0 + ty * 4 + i);
        int jb = j0 + tx * 4;
        float4 o;
        o.x = acc[i][0] + bias[jb + 0];
        o.y = acc[i][1] + bias[jb + 1];
        o.z = acc[i][2] + bias[jb + 2];
        o.w = acc[i][3] + bias[jb + 3];
        *(float4*)&gates[row * 512 + jb] = o;
    }
}

// ---------------- LSTM cell elementwise ----------------
__global__ void cell_kernel(const float* __restrict__ gates,
                            const float* __restrict__ c_prev, int c_stride,
                            float* __restrict__ c_out,
                            float* __restrict__ h_out, int h_stride,
                            int total) {
    int t = blockIdx.x * blockDim.x + threadIdx.x;
    if (t >= total) return;
    int g = t >> 7, k = t & (D - 1);
    const float* grow = gates + (size_t)g * 512;
    float ig = grow[k];
    float fg = grow[D + k];
    float gg = grow[2 * D + k];
    float og = grow[3 * D + k];
    float cp = c_prev[(size_t)g * c_stride + k];
    float c = sigmoidf_(fg) * cp + sigmoidf_(ig) * tanhf(gg);
    float h = sigmoidf_(og) * tanhf(c);
    c_out[t] = c;
    h_out[(size_t)g * h_stride + k] = h;
}

extern "C" void kernel_launch(void* const* d_in, const int* in_sizes, int n_in,
                              void* d_out, int out_size, void* d_ws, size_t ws_size,
                              hipStream_t stream) {
    const float* x      = (const float*)d_in[0];
    const float* W_ih   = (const float*)d_in[1];
    const float* W_hh   = (const float*)d_in[2];
    const float* b_ih   = (const float*)d_in[3];
    const float* b_hh   = (const float*)d_in[4];
    const int*   index  = (const int*)d_in[5];
    int N = in_sizes[5];
    int G = out_size / (2 * D);
    float* out = (float*)d_out;
    size_t totalx = (size_t)N * D;

    float* ws = (float*)d_ws;
    __half* xh    = (__half*)ws;                        // N*D halfs (= N*D/2 floats)
    float* Wc     = ws + totalx / 2;                    // 512*D
    float* b_sum  = Wc + 4 * D * D;                     // 512
    float* h1     = b_sum + 4 * D;                      // D
    float* c1     = h1 + D;                             // D
    float* r1     = c1 + D;                             // G*D
    float* h2     = r1 + (size_t)G * D;                 // G*D
    float* c2     = h2 + (size_t)G * D;                 // G*D
    float* r2     = c2 + (size_t)G * D;                 // G*D
    float* gatesb = r2 + (size_t)G * D;                 // G*4D
    int* seg_off  = (int*)(gatesb + (size_t)G * 4 * D); // G+1
    float* c3     = r1;  // r1 dead after step-3 GEMM; c3 never read

    prep_kernel<<<274, 256, 0, stream>>>(W_ih, W_hh, b_ih, b_hh, index, N, G,
                                         Wc, seg_off, b_sum, h1, c1);
    x_to_h_kernel<<<(int)((totalx / 8 + 255) / 256), 256, 0, stream>>>(x, xh, totalx);

    // ---- step 1: attention with broadcast q = h1
    attn_kernel<<<G, 256, 0, stream>>>(xh, seg_off, h1, 0, r1, D, G);

    // ---- step 2
    gates_gemm_kernel<<<dim3(G / 64, 8), 256, 0, stream>>>(
        h1, 0, Wc, r1, W_ih + D, 2 * D, b_sum, gatesb);
    cell_kernel<<<(G * D + 255) / 256, 256, 0, stream>>>(gatesb, c1, 0, c2, h2, D, G * D);
    attn_kernel<<<G, 256, 0, stream>>>(xh, seg_off, h2, D, r2, D, G);

    // ---- step 3
    gates_gemm_kernel<<<dim3(G / 64, 8), 256, 0, stream>>>(
        h2, D, Wc, r2, W_ih + D, 2 * D, b_sum, gatesb);
    cell_kernel<<<(G * D + 255) / 256, 256, 0, stream>>>(gatesb, c2, D, c3, out, 2 * D, G * D);
    attn_kernel<<<G, 256, 0, stream>>>(xh, seg_off, out, 2 * D, out + D, 2 * D, G);
}